// Round 1
// baseline (6338.726 us; speedup 1.0000x reference)
//
#include <hip/hip_runtime.h>

#define NB 64      // batch
#define NT 512     // time
#define ND 512     // input dim
#define NH 768     // hidden
#define KTOT 1280  // ND + NH
#define NG 3072    // 4*NH
#define NROW (NB * NT)  // 32768 rows of x
#define NHG 48          // h-groups (NH/16)

typedef short bf16x8 __attribute__((ext_vector_type(8)));
typedef float f32x4 __attribute__((ext_vector_type(4)));

__device__ __forceinline__ unsigned short f2b(float f) {
    unsigned int u; __builtin_memcpy(&u, &f, 4);
    u = u + 0x7FFFu + ((u >> 16) & 1u);   // round-to-nearest-even
    return (unsigned short)(u >> 16);
}
__device__ __forceinline__ float sigmoidf_(float x) { return 1.f / (1.f + __expf(-x)); }
__device__ __forceinline__ float tanhf_(float x) { return 2.f / (1.f + __expf(-2.f * x)) - 1.f; }

// -------- W transpose+convert: W[KTOT][NG] f32 -> WT[NG][KTOT] bf16 --------
__global__ __launch_bounds__(256) void transpose_w(const float* __restrict__ W,
                                                   unsigned short* __restrict__ WT) {
    __shared__ float tile[64][65];
    int bx = blockIdx.x % (NG / 64);   // col tile
    int by = blockIdx.x / (NG / 64);   // k tile
    int cb = bx * 64, kb = by * 64;
    int tid = threadIdx.x;
    {
        int r = tid >> 2;
        int coff = (tid & 3) * 16;
        const float* src = W + (size_t)(kb + r) * NG + cb + coff;
#pragma unroll
        for (int i = 0; i < 16; i += 4) {
            float4 v = *(const float4*)(src + i);
            tile[coff + i][r] = v.x; tile[coff + i + 1][r] = v.y;
            tile[coff + i + 2][r] = v.z; tile[coff + i + 3][r] = v.w;
        }
    }
    __syncthreads();
    {
        int c = tid >> 2;
        int koff = (tid & 3) * 16;
        bf16x8 o0, o1;
#pragma unroll
        for (int i = 0; i < 8; ++i) {
            o0[i] = (short)f2b(tile[c][koff + i]);
            o1[i] = (short)f2b(tile[c][koff + 8 + i]);
        }
        unsigned short* dst = WT + (size_t)(cb + c) * KTOT + kb + koff;
        *(bf16x8*)dst       = o0;
        *(bf16x8*)(dst + 8) = o1;
    }
}

// -------- x f32 -> bf16 (fallback path only) --------
__global__ __launch_bounds__(256) void convert_x(const float* __restrict__ src,
                                                 unsigned short* __restrict__ dst, int n8) {
    int i = blockIdx.x * 256 + threadIdx.x;
    if (i < n8) {
        const float4* s = (const float4*)(src + (size_t)i * 8);
        float4 v0 = s[0], v1 = s[1];
        bf16x8 o;
        o[0] = (short)f2b(v0.x); o[1] = (short)f2b(v0.y);
        o[2] = (short)f2b(v0.z); o[3] = (short)f2b(v0.w);
        o[4] = (short)f2b(v1.x); o[5] = (short)f2b(v1.y);
        o[6] = (short)f2b(v1.z); o[7] = (short)f2b(v1.w);
        *(bf16x8*)(dst + (size_t)i * 8) = o;
    }
}

// -------- precompute x-part gates: Gx = x @ Wx + bias (+1 on f gate) --------
// Gx layout: [dir][hg(48)][row=b*NT+t][gate(4)][hl(16)] f32 -> each persistent
// block reads a contiguous 256B chunk per (row, step).
// Grid: 2 dirs x 512 row-blocks (64 rows each); 256 thr; wave == gate.
__global__ __launch_bounds__(256) void gemm_xw(
    const float* __restrict__ seq,
    const unsigned short* __restrict__ WT,
    const float* __restrict__ b_fw,
    const float* __restrict__ b_bw,
    float* __restrict__ Gx) {
    __shared__ unsigned short Albs[64 * 520];   // 64 rows x 512 k, pitch 520 (pad)
    int blk = blockIdx.x;
    int dir = blk >> 9;
    int mb = (blk & 511) * 64;
    const float* bias = dir ? b_bw : b_fw;
    const unsigned short* Wd = WT + (size_t)dir * NG * KTOT;
    int tid = threadIdx.x;
    // stage A: row = tid>>2, 4 threads/row, 128 k each, f32 -> bf16
    {
        int r = tid >> 2;
        int k0 = (tid & 3) * 128;
        const float* src = seq + (size_t)(mb + r) * ND + k0;
        unsigned short* dst = Albs + r * 520 + k0;
#pragma unroll
        for (int i = 0; i < 16; ++i) {
            float4 v0 = *(const float4*)(src + i * 8);
            float4 v1 = *(const float4*)(src + i * 8 + 4);
            bf16x8 o;
            o[0] = (short)f2b(v0.x); o[1] = (short)f2b(v0.y);
            o[2] = (short)f2b(v0.z); o[3] = (short)f2b(v0.w);
            o[4] = (short)f2b(v1.x); o[5] = (short)f2b(v1.y);
            o[6] = (short)f2b(v1.z); o[7] = (short)f2b(v1.w);
            *(bf16x8*)(dst + i * 8) = o;
        }
    }
    __syncthreads();
    int lane = tid & 63, wave = tid >> 6;
    int r0 = lane & 15, qq = lane >> 4, q8 = qq * 8;
#pragma unroll 1
    for (int nc = 0; nc < 12; ++nc) {
        int colbase = wave * NH + nc * 64;       // gate == wave
        f32x4 acc[4][4];
#pragma unroll
        for (int nt = 0; nt < 4; ++nt) {
            float bv = bias[colbase + nt * 16 + r0] + (wave == 2 ? 1.0f : 0.0f);
#pragma unroll
            for (int m = 0; m < 4; ++m) {
                acc[m][nt][0] = bv; acc[m][nt][1] = bv;
                acc[m][nt][2] = bv; acc[m][nt][3] = bv;
            }
        }
        const unsigned short* bp0 = Wd + (size_t)(colbase + r0) * KTOT + q8;
#pragma unroll
        for (int ks = 0; ks < 16; ++ks) {
            bf16x8 a[4], bb[4];
#pragma unroll
            for (int m = 0; m < 4; ++m)
                a[m] = *(const bf16x8*)&Albs[(m * 16 + r0) * 520 + ks * 32 + q8];
#pragma unroll
            for (int nt = 0; nt < 4; ++nt)
                bb[nt] = *(const bf16x8*)(bp0 + (size_t)nt * 16 * KTOT + ks * 32);
#pragma unroll
            for (int m = 0; m < 4; ++m)
#pragma unroll
                for (int nt = 0; nt < 4; ++nt)
                    acc[m][nt] = __builtin_amdgcn_mfma_f32_16x16x32_bf16(a[m], bb[nt], acc[m][nt], 0, 0, 0);
        }
        // write: hg = nc*4+nt, gate = wave, hl = r0
#pragma unroll
        for (int nt = 0; nt < 4; ++nt) {
            float* gp = Gx + ((size_t)(dir * NHG + nc * 4 + nt) * NROW) * 64 + wave * 16 + r0;
#pragma unroll
            for (int m = 0; m < 4; ++m) {
#pragma unroll
                for (int r = 0; r < 4; ++r) {
                    int row = mb + m * 16 + qq * 4 + r;
                    gp[(size_t)row * 64] = acc[m][nt][r];
                }
            }
        }
    }
}

// ---------------- persistent bidirectional LSTM ----------------
// 192 blocks = dir(2) x bgroup(2) x hgroup(48); 256 threads; 1 block/CU.
// mode: 0 = in-loop x from f32, 1 = in-loop x from bf16, 2 = precomputed Gx.
// Per step (mode 2): stage h -> 24-ks h-GEMM (Wh in regs) -> gl bounce ->
// epilogue -> barrier (Gx prefetch for step+1 issued under the spin).
__global__ __launch_bounds__(256, 1) void lstm_persistent(
    const float* __restrict__ seq,
    const unsigned short* __restrict__ xbf,
    int mode,
    const int* __restrict__ seq_len,
    const unsigned short* __restrict__ WT,       // [2][NG][KTOT] bf16
    const float* __restrict__ bias_fw,
    const float* __restrict__ bias_bw,
    const float* __restrict__ Gx,                // [2][48][NROW][64] f32
    unsigned short* __restrict__ hbufs,          // [3][2][NB][NH] bf16
    float* __restrict__ h_final,                 // [2][NB][NH] f32
    float* __restrict__ out,                     // [NB][NT][2*NH] f32
    unsigned int* __restrict__ barrier_cnts)     // 4 counters, 256B apart
{
    extern __shared__ char smem[];
    unsigned short* A = (unsigned short*)smem;   // [32][776] staging
    float* gl = (float*)smem;                    // overlay: [4][32][17] f32 (8.7KB)

    int bid = blockIdx.x;
    int hgroup = bid % NHG;
    int bgroup = (bid / NHG) & 1;
    int dir = bid / (2 * NHG);
    int grp = bid / NHG;                         // barrier group 0..3
    int b0 = bgroup * 32;
    int hbase = hgroup * 16;
    int tid = threadIdx.x;
    int lane = tid & 63;
    int wave = tid >> 6;                         // = gate index
    int r0 = lane & 15;
    int qq = lane >> 4;
    int q8 = qq * 8;

    const unsigned short* Wd = WT + (size_t)dir * NG * KTOT;
    const float* bias = dir ? bias_bw : bias_fw;
    int col = wave * NH + hbase + r0;
    const unsigned short* BpX = Wd + (size_t)col * KTOT + q8;   // x-part B (fallback)
    float bv = bias[col] + (wave == 2 ? 1.0f : 0.0f);           // forget bias folded

    // ---- Wh (h-part B fragments) -> registers, once ----
    bf16x8 wb[24];
    {
        const unsigned short* whp = Wd + (size_t)col * KTOT + ND + q8;
#pragma unroll
        for (int ks = 0; ks < 24; ++ks) wb[ks] = *(const bf16x8*)(whp + ks * 32);
    }

    // ---- per-thread staging constants ----
    int srow = tid >> 3;                         // staging row 0..31
    int sb = b0 + srow;
    int Ls = seq_len[sb];
    int koff0 = (tid & 7) * 8;
    const float* xrow_f = seq + (size_t)sb * NT * ND;
    const unsigned short* xrow_b = (mode == 1) ? (xbf + (size_t)sb * NT * ND)
                                               : (const unsigned short*)0;

    // ---- epilogue constants ----
    int ebl0 = tid >> 4;
    int ehl = tid & 15;
    int hidx = hbase + ehl;
    int Lb[2]; Lb[0] = seq_len[b0 + ebl0]; Lb[1] = seq_len[b0 + ebl0 + 16];
    float c_reg[2] = {0.f, 0.f};
    unsigned short h_reg[2] = {0, 0};

    // ---- Gx prefetch state (mode 2): 8 rows per thread ----
    const float* gxp[8];
    int Ls8[8];
    float gx[8];
    if (mode == 2) {
        const float* gxbase = Gx + ((size_t)(dir * NHG + hgroup) * NROW) * 64 + wave * 16 + r0;
#pragma unroll
        for (int i = 0; i < 8; ++i) {
            int br = b0 + qq * 4 + (i & 3) + (i >> 2) * 16;
            Ls8[i] = seq_len[br];
            gxp[i] = gxbase + (size_t)br * NT * 64;
            int tn = dir ? (Ls8[i] - 1) : 0;     // step 0
            if (tn < 0) tn = 0;
            gx[i] = gxp[i][(size_t)tn * 64];
        }
    }

    unsigned int* cnt = barrier_cnts + grp * 64; // 256B apart

    for (int step = 0; step < NT; ++step) {
        const unsigned short* hin = hbufs + (size_t)(step % 3) * (2 * NB * NH) + (size_t)dir * NB * NH;
        unsigned short* hout      = hbufs + (size_t)((step + 1) % 3) * (2 * NB * NH) + (size_t)dir * NB * NH;

        f32x4 acc0, acc1;

        if (mode < 2) {
            // ---- fallback: in-loop x-part ----
            int t_in = dir ? (Ls - 1 - step) : step;
            if (t_in < 0) t_in = 0;
            if (mode == 1) {
                const unsigned short* xr = xrow_b + (size_t)t_in * ND;
#pragma unroll
                for (int i = 0; i < 8; ++i) {
                    int kl = koff0 + i * 64;
                    *(bf16x8*)&A[srow * 776 + kl] = *(const bf16x8*)(xr + kl);
                }
            } else {
                const float* xr = xrow_f + (size_t)t_in * ND;
#pragma unroll
                for (int i = 0; i < 8; ++i) {
                    int kl = koff0 + i * 64;
                    float4 v0 = *(const float4*)(xr + kl);
                    float4 v1 = *(const float4*)(xr + kl + 4);
                    bf16x8 o;
                    o[0] = (short)f2b(v0.x); o[1] = (short)f2b(v0.y);
                    o[2] = (short)f2b(v0.z); o[3] = (short)f2b(v0.w);
                    o[4] = (short)f2b(v1.x); o[5] = (short)f2b(v1.y);
                    o[6] = (short)f2b(v1.z); o[7] = (short)f2b(v1.w);
                    *(bf16x8*)&A[srow * 776 + kl] = o;
                }
            }
            __syncthreads();
            acc0[0] = bv; acc0[1] = bv; acc0[2] = bv; acc0[3] = bv;
            acc1 = acc0;
#pragma unroll
            for (int ks = 0; ks < 16; ++ks) {
                bf16x8 a0 = *(const bf16x8*)&A[r0 * 776 + ks * 32 + q8];
                bf16x8 a1 = *(const bf16x8*)&A[(r0 + 16) * 776 + ks * 32 + q8];
                bf16x8 bf = *(const bf16x8*)(BpX + ks * 32);
                acc0 = __builtin_amdgcn_mfma_f32_16x16x32_bf16(a0, bf, acc0, 0, 0, 0);
                acc1 = __builtin_amdgcn_mfma_f32_16x16x32_bf16(a1, bf, acc1, 0, 0, 0);
            }
            __syncthreads();
        }

        // ---- stage h (k 0..767 of A) ----
        {
            const unsigned short* hr = hin + (size_t)sb * NH;
#pragma unroll
            for (int i = 0; i < 12; ++i) {
                int kl = koff0 + i * 64;
                *(bf16x8*)&A[srow * 776 + kl] = *(const bf16x8*)(hr + kl);
            }
        }
        if (mode == 2) {
            acc0[0] = gx[0]; acc0[1] = gx[1]; acc0[2] = gx[2]; acc0[3] = gx[3];
            acc1[0] = gx[4]; acc1[1] = gx[5]; acc1[2] = gx[6]; acc1[3] = gx[7];
        }
        __syncthreads();
#pragma unroll
        for (int ks = 0; ks < 24; ++ks) {
            bf16x8 a0 = *(const bf16x8*)&A[r0 * 776 + ks * 32 + q8];
            bf16x8 a1 = *(const bf16x8*)&A[(r0 + 16) * 776 + ks * 32 + q8];
            acc0 = __builtin_amdgcn_mfma_f32_16x16x32_bf16(a0, wb[ks], acc0, 0, 0, 0);
            acc1 = __builtin_amdgcn_mfma_f32_16x16x32_bf16(a1, wb[ks], acc1, 0, 0, 0);
        }
        __syncthreads();                          // A reads done; gl overlay safe

        // C/D layout: col = lane&15, row = (lane>>4)*4 + reg; gl pitch 17 (pad)
#pragma unroll
        for (int r = 0; r < 4; ++r) {
            gl[(wave * 32 + qq * 4 + r) * 17 + r0] = acc0[r];
            gl[(wave * 32 + 16 + qq * 4 + r) * 17 + r0] = acc1[r];
        }
        __syncthreads();

        // ---- epilogue: cell update, c/h in registers ----
#pragma unroll
        for (int it = 0; it < 2; ++it) {
            int bl = ebl0 + it * 16;
            int bb = b0 + bl;
            if (step < Lb[it]) {
                float gi = gl[(0 * 32 + bl) * 17 + ehl];
                float gj = gl[(1 * 32 + bl) * 17 + ehl];
                float gf = gl[(2 * 32 + bl) * 17 + ehl];
                float go = gl[(3 * 32 + bl) * 17 + ehl];
                float nc = c_reg[it] * sigmoidf_(gf) + sigmoidf_(gi) * tanhf_(gj);
                float nh = tanhf_(nc) * sigmoidf_(go);
                c_reg[it] = nc;
                h_reg[it] = f2b(nh);
                if (step == Lb[it] - 1)
                    h_final[((size_t)dir * NB + bb) * NH + hidx] = nh;
                int t_out = dir ? (Lb[it] - 1 - step) : step;
                out[((size_t)bb * NT + t_out) * (2 * NH) + dir * NH + hidx] = nh;
            } else {
                // masked: dynamic_rnn zeros outputs (no host-side memset)
                out[((size_t)bb * NT + step) * (2 * NH) + dir * NH + hidx] = 0.f;
            }
            hout[(size_t)bb * NH + hidx] = h_reg[it];
        }

        __syncthreads();                          // drain h/out stores before release

        // ---- prefetch next step's Gx (hides HBM latency under barrier) ----
        if (mode == 2) {
            int stepn = step + 1;
#pragma unroll
            for (int i = 0; i < 8; ++i) {
                int tn = dir ? (Ls8[i] - 1 - stepn) : stepn;
                tn = tn < 0 ? 0 : (tn > NT - 1 ? NT - 1 : tn);
                gx[i] = gxp[i][(size_t)tn * 64];
            }
        }

        // ---- group barrier (48 blocks sharing this dir+bgroup's h state) ----
        if (tid == 0) {
            __hip_atomic_fetch_add(cnt, 1u, __ATOMIC_RELEASE, __HIP_MEMORY_SCOPE_AGENT);
            unsigned int tgt = 48u * (unsigned)(step + 1);
            while (__hip_atomic_load(cnt, __ATOMIC_RELAXED, __HIP_MEMORY_SCOPE_AGENT) < tgt)
                __builtin_amdgcn_s_sleep(2);
            (void)__hip_atomic_load(cnt, __ATOMIC_ACQUIRE, __HIP_MEMORY_SCOPE_AGENT);
        }
        __syncthreads();
    }
}

// ---------------- final hidden state (f32) -> d_out tail ----------------
__global__ __launch_bounds__(256) void write_state(const float* __restrict__ h_final,
                                                   float* __restrict__ out_state) {
    int i = blockIdx.x * 256 + threadIdx.x;      // over 2*NB*NH
    if (i < 2 * NB * NH) {
        int dir = i / (NB * NH);
        int rem = i - dir * (NB * NH);
        int b = rem / NH, h = rem - (rem / NH) * NH;
        out_state[(size_t)b * (2 * NH) + dir * NH + h] = h_final[i];
    }
}

extern "C" void kernel_launch(void* const* d_in, const int* in_sizes, int n_in,
                              void* d_out, int out_size, void* d_ws, size_t ws_size,
                              hipStream_t stream) {
    const float* seq   = (const float*)d_in[0];
    const int* seq_len = (const int*)d_in[1];
    const float* W_fw  = (const float*)d_in[2];
    const float* b_fw  = (const float*)d_in[3];
    const float* W_bw  = (const float*)d_in[4];
    const float* b_bw  = (const float*)d_in[5];
    float* out = (float*)d_out;

    char* ws = (char*)d_ws;
    size_t off = 0;
    unsigned short* WT = (unsigned short*)(ws + off);  off += (size_t)2 * NG * KTOT * 2; // 15,728,640
    unsigned short* hbufs = (unsigned short*)(ws + off);
    size_t hbuf_bytes = (size_t)3 * 2 * NB * NH * 2;   off += hbuf_bytes;                // 589,824
    float* h_final = (float*)(ws + off);
    size_t hf_bytes = (size_t)2 * NB * NH * 4;         off += hf_bytes;                  // 393,216
    unsigned int* barrier_cnts = (unsigned int*)(ws + off);
    size_t bar_bytes = 1024;                           off += bar_bytes;

    // Gx and xbf share the tail of the workspace (only one is used).
    float* Gx = (float*)(ws + off);
    size_t gx_bytes = (size_t)2 * NHG * NROW * 64 * 4;   // 805,306,368
    unsigned short* xbf = (unsigned short*)(ws + off);
    size_t xbf_bytes = (size_t)NB * NT * ND * 2;         // 33,554,432

    int mode = (ws_size >= off + gx_bytes) ? 2
             : ((ws_size >= off + xbf_bytes) ? 1 : 0);

    // zero h buffers / h_final / barrier counters (contiguous). out is fully
    // written by the kernel (masked positions write exact 0), no big memset.
    hipMemsetAsync(hbufs, 0, hbuf_bytes + hf_bytes + bar_bytes, stream);

    transpose_w<<<(KTOT / 64) * (NG / 64), 256, 0, stream>>>(W_fw, WT);
    transpose_w<<<(KTOT / 64) * (NG / 64), 256, 0, stream>>>(W_bw, WT + (size_t)NG * KTOT);

    if (mode == 2) {
        gemm_xw<<<1024, 256, 0, stream>>>(seq, WT, b_fw, b_bw, Gx);
    } else if (mode == 1) {
        int n8 = NB * NT * ND / 8;
        convert_x<<<(n8 + 255) / 256, 256, 0, stream>>>(seq, xbf, n8);
    }

    size_t smem_bytes = (size_t)32 * 776 * 2;            // 49,664 (A + gl overlay)
    lstm_persistent<<<192, 256, smem_bytes, stream>>>(
        seq, xbf, mode, seq_len, WT, b_fw, b_bw, Gx,
        hbufs, h_final, out, barrier_cnts);

    write_state<<<(2 * NB * NH + 255) / 256, 256, 0, stream>>>(
        h_final, out + (size_t)NB * NT * 2 * NH);
}

// Round 2
// 3261.322 us; speedup vs baseline: 1.9436x; 1.9436x over previous
//
#include <hip/hip_runtime.h>

#define NB 64      // batch
#define NT 512     // time
#define ND 512     // input dim
#define NH 768     // hidden
#define KTOT 1280  // ND + NH
#define NG 3072    // 4*NH
#define NROW (NB * NT)  // 32768 rows of x
#define NHG 48          // h-groups (NH/16)

typedef short bf16x8 __attribute__((ext_vector_type(8)));
typedef float f32x4 __attribute__((ext_vector_type(4)));

__device__ __forceinline__ unsigned short f2b(float f) {
    unsigned int u; __builtin_memcpy(&u, &f, 4);
    u = u + 0x7FFFu + ((u >> 16) & 1u);   // round-to-nearest-even
    return (unsigned short)(u >> 16);
}
__device__ __forceinline__ float sigmoidf_(float x) { return 1.f / (1.f + __expf(-x)); }
__device__ __forceinline__ float tanhf_(float x) { return 2.f / (1.f + __expf(-2.f * x)) - 1.f; }

// -------- W transpose+convert: W[KTOT][NG] f32 -> WT[NG][KTOT] bf16 --------
__global__ __launch_bounds__(256) void transpose_w(const float* __restrict__ W,
                                                   unsigned short* __restrict__ WT) {
    __shared__ float tile[64][65];
    int bx = blockIdx.x % (NG / 64);   // col tile
    int by = blockIdx.x / (NG / 64);   // k tile
    int cb = bx * 64, kb = by * 64;
    int tid = threadIdx.x;
    {
        int r = tid >> 2;
        int coff = (tid & 3) * 16;
        const float* src = W + (size_t)(kb + r) * NG + cb + coff;
#pragma unroll
        for (int i = 0; i < 16; i += 4) {
            float4 v = *(const float4*)(src + i);
            tile[coff + i][r] = v.x; tile[coff + i + 1][r] = v.y;
            tile[coff + i + 2][r] = v.z; tile[coff + i + 3][r] = v.w;
        }
    }
    __syncthreads();
    {
        int c = tid >> 2;
        int koff = (tid & 3) * 16;
        bf16x8 o0, o1;
#pragma unroll
        for (int i = 0; i < 8; ++i) {
            o0[i] = (short)f2b(tile[c][koff + i]);
            o1[i] = (short)f2b(tile[c][koff + 8 + i]);
        }
        unsigned short* dst = WT + (size_t)(cb + c) * KTOT + kb + koff;
        *(bf16x8*)dst       = o0;
        *(bf16x8*)(dst + 8) = o1;
    }
}

// -------- x f32 -> bf16 (modes 1/2 fallback chain) --------
__global__ __launch_bounds__(256) void convert_x(const float* __restrict__ src,
                                                 unsigned short* __restrict__ dst, int n8) {
    int i = blockIdx.x * 256 + threadIdx.x;
    if (i < n8) {
        const float4* s = (const float4*)(src + (size_t)i * 8);
        float4 v0 = s[0], v1 = s[1];
        bf16x8 o;
        o[0] = (short)f2b(v0.x); o[1] = (short)f2b(v0.y);
        o[2] = (short)f2b(v0.z); o[3] = (short)f2b(v0.w);
        o[4] = (short)f2b(v1.x); o[5] = (short)f2b(v1.y);
        o[6] = (short)f2b(v1.z); o[7] = (short)f2b(v1.w);
        *(bf16x8*)(dst + (size_t)i * 8) = o;
    }
}

// -------- precompute x-part gates (mode 2 only, needs ~805MB ws) --------
__global__ __launch_bounds__(256) void gemm_xw(
    const float* __restrict__ seq,
    const unsigned short* __restrict__ WT,
    const float* __restrict__ b_fw,
    const float* __restrict__ b_bw,
    float* __restrict__ Gx) {
    __shared__ unsigned short Albs[64 * 520];
    int blk = blockIdx.x;
    int dir = blk >> 9;
    int mb = (blk & 511) * 64;
    const float* bias = dir ? b_bw : b_fw;
    const unsigned short* Wd = WT + (size_t)dir * NG * KTOT;
    int tid = threadIdx.x;
    {
        int r = tid >> 2;
        int k0 = (tid & 3) * 128;
        const float* src = seq + (size_t)(mb + r) * ND + k0;
        unsigned short* dst = Albs + r * 520 + k0;
#pragma unroll
        for (int i = 0; i < 16; ++i) {
            float4 v0 = *(const float4*)(src + i * 8);
            float4 v1 = *(const float4*)(src + i * 8 + 4);
            bf16x8 o;
            o[0] = (short)f2b(v0.x); o[1] = (short)f2b(v0.y);
            o[2] = (short)f2b(v0.z); o[3] = (short)f2b(v0.w);
            o[4] = (short)f2b(v1.x); o[5] = (short)f2b(v1.y);
            o[6] = (short)f2b(v1.z); o[7] = (short)f2b(v1.w);
            *(bf16x8*)(dst + i * 8) = o;
        }
    }
    __syncthreads();
    int lane = tid & 63, wave = tid >> 6;
    int r0 = lane & 15, qq = lane >> 4, q8 = qq * 8;
#pragma unroll 1
    for (int nc = 0; nc < 12; ++nc) {
        int colbase = wave * NH + nc * 64;
        f32x4 acc[4][4];
#pragma unroll
        for (int nt = 0; nt < 4; ++nt) {
            float bv = bias[colbase + nt * 16 + r0] + (wave == 2 ? 1.0f : 0.0f);
#pragma unroll
            for (int m = 0; m < 4; ++m) {
                acc[m][nt][0] = bv; acc[m][nt][1] = bv;
                acc[m][nt][2] = bv; acc[m][nt][3] = bv;
            }
        }
        const unsigned short* bp0 = Wd + (size_t)(colbase + r0) * KTOT + q8;
#pragma unroll
        for (int ks = 0; ks < 16; ++ks) {
            bf16x8 a[4], bb[4];
#pragma unroll
            for (int m = 0; m < 4; ++m)
                a[m] = *(const bf16x8*)&Albs[(m * 16 + r0) * 520 + ks * 32 + q8];
#pragma unroll
            for (int nt = 0; nt < 4; ++nt)
                bb[nt] = *(const bf16x8*)(bp0 + (size_t)nt * 16 * KTOT + ks * 32);
#pragma unroll
            for (int m = 0; m < 4; ++m)
#pragma unroll
                for (int nt = 0; nt < 4; ++nt)
                    acc[m][nt] = __builtin_amdgcn_mfma_f32_16x16x32_bf16(a[m], bb[nt], acc[m][nt], 0, 0, 0);
        }
#pragma unroll
        for (int nt = 0; nt < 4; ++nt) {
            float* gp = Gx + ((size_t)(dir * NHG + nc * 4 + nt) * NROW) * 64 + wave * 16 + r0;
#pragma unroll
            for (int m = 0; m < 4; ++m) {
#pragma unroll
                for (int r = 0; r < 4; ++r) {
                    int row = mb + m * 16 + qq * 4 + r;
                    gp[(size_t)row * 64] = acc[m][nt][r];
                }
            }
        }
    }
}

// ---------------- persistent bidirectional LSTM ----------------
// 192 blocks = dir(2) x bgroup(2) x hgroup(48); 256 threads; 1 block/CU.
// Key changes vs prior round:
//  * h exchange is device-scope (sc1, L2-bypass) via __hip_atomic ops; barrier
//    atomics are RELAXED -> NO buffer_wbl2/buffer_inv per step, W/x stay in L2.
//    (Correctness: __syncthreads drains each wave's sc1 stores (vmcnt0) before
//    tid0's arrive-add; readers' h loads are sc1 so they can't hit stale L2.)
//  * Wh restored to LDS (register experiment regressed: compiler sank the 96
//    VGPR array into per-step global reloads).
//  * x-GEMM for step t+1 runs between barrier-arrive and barrier-poll, hiding
//    it under barrier skew; only the h path remains serial.
__global__ __launch_bounds__(256, 1) void lstm_persistent(
    const float* __restrict__ seq,
    const unsigned short* __restrict__ xbf,
    int mode,                                    // 0: x f32 in-loop, 1: x bf16 in-loop, 2: Gx
    const int* __restrict__ seq_len,
    const unsigned short* __restrict__ WT,       // [2][NG][KTOT] bf16
    const float* __restrict__ bias_fw,
    const float* __restrict__ bias_bw,
    const float* __restrict__ Gx,                // [2][48][NROW][64] f32 (mode 2)
    unsigned short* __restrict__ hbufs,          // [3][2][NB][NH] bf16
    float* __restrict__ h_final,                 // [2][NB][NH] f32
    float* __restrict__ out,                     // [NB][NT][2*NH] f32
    unsigned int* __restrict__ barrier_cnts)     // 4 counters, 256B apart
{
    extern __shared__ char smem[];
    unsigned short* Wh = (unsigned short*)smem;                  // [64][776] bf16
    unsigned short* A  = (unsigned short*)(smem + 64 * 776 * 2); // [32][776] staging
    float* gl = (float*)(smem + 64 * 776 * 2);                   // overlay: [4][32][17]

    int bid = blockIdx.x;
    int hgroup = bid % NHG;
    int bgroup = (bid / NHG) & 1;
    int dir = bid / (2 * NHG);
    int grp = bid / NHG;                         // barrier group 0..3
    int b0 = bgroup * 32;
    int hbase = hgroup * 16;
    int tid = threadIdx.x;
    int lane = tid & 63;
    int wave = tid >> 6;                         // = gate index
    int r0 = lane & 15;
    int qq = lane >> 4;
    int q8 = qq * 8;

    const unsigned short* Wd = WT + (size_t)dir * NG * KTOT;
    const float* bias = dir ? bias_bw : bias_fw;
    int col = wave * NH + hbase + r0;
    const unsigned short* BpX = Wd + (size_t)col * KTOT + q8;        // x-part B (global, L2-hot)
    const unsigned short* WhB = Wh + (size_t)(wave * 16 + r0) * 776 + q8;
    float bv = bias[col] + (wave == 2 ? 1.0f : 0.0f);                // forget bias folded

    // ---- fill Wh (h-part of this block's 64 gate-cols) into LDS, once ----
    {
        int rl = tid >> 2;
        int gcol = (rl >> 4) * NH + hbase + (rl & 15);
        const unsigned short* src = Wd + (size_t)gcol * KTOT + ND;
        unsigned short* dstrow = Wh + rl * 776;
#pragma unroll
        for (int i = 0; i < 24; ++i) {
            int off = (tid & 3) * 8 + i * 32;
            *(bf16x8*)(dstrow + off) = *(const bf16x8*)(src + off);
        }
    }

    // ---- per-thread staging constants ----
    int srow = tid >> 3;                         // staging row 0..31
    int sb = b0 + srow;
    int Ls = seq_len[sb];
    int koff0 = (tid & 7) * 8;
    const float* xrow_f = seq + (size_t)sb * NT * ND;
    const unsigned short* xrow_b = xbf + (size_t)sb * NT * ND;

    // ---- epilogue constants ----
    int ebl0 = tid >> 4;
    int ehl = tid & 15;
    int hidx = hbase + ehl;
    int Lb[2]; Lb[0] = seq_len[b0 + ebl0]; Lb[1] = seq_len[b0 + ebl0 + 16];
    float c_reg[2] = {0.f, 0.f};
    unsigned short h_reg[2] = {0, 0};

    // ---- x prefetch / Gx prefetch state ----
    bf16x8 xreg[8];
    f32x4 ax0, ax1;                              // bias + x-part, for current step
    const float* gxp[8];
    int Ls8[8];
    float gx[8];

    if (mode == 2) {
        const float* gxbase = Gx + ((size_t)(dir * NHG + hgroup) * NROW) * 64 + wave * 16 + r0;
#pragma unroll
        for (int i = 0; i < 8; ++i) {
            int br = b0 + qq * 4 + (i & 3) + (i >> 2) * 16;
            Ls8[i] = seq_len[br];
            gxp[i] = gxbase + (size_t)br * NT * 64;
            int tn = dir ? (Ls8[i] - 1) : 0;     // step 0
            if (tn < 0) tn = 0;
            gx[i] = gxp[i][(size_t)tn * 64];
        }
    } else {
        // prologue: stage x(0) and run x-GEMM(0)
        int t0 = dir ? (Ls - 1) : 0;
        if (t0 < 0) t0 = 0;
        if (mode == 1) {
            const unsigned short* xr = xrow_b + (size_t)t0 * ND;
#pragma unroll
            for (int i = 0; i < 8; ++i) xreg[i] = *(const bf16x8*)(xr + koff0 + i * 64);
        } else {
            const float* xr = xrow_f + (size_t)t0 * ND;
#pragma unroll
            for (int i = 0; i < 8; ++i) {
                float4 v0 = *(const float4*)(xr + koff0 + i * 64);
                float4 v1 = *(const float4*)(xr + koff0 + i * 64 + 4);
                bf16x8 o;
                o[0] = (short)f2b(v0.x); o[1] = (short)f2b(v0.y);
                o[2] = (short)f2b(v0.z); o[3] = (short)f2b(v0.w);
                o[4] = (short)f2b(v1.x); o[5] = (short)f2b(v1.y);
                o[6] = (short)f2b(v1.z); o[7] = (short)f2b(v1.w);
                xreg[i] = o;
            }
        }
#pragma unroll
        for (int i = 0; i < 8; ++i)
            *(bf16x8*)&A[srow * 776 + koff0 + i * 64] = xreg[i];
    }
    __syncthreads();                             // Wh fill + A-x visible
    if (mode != 2) {
        ax0[0] = bv; ax0[1] = bv; ax0[2] = bv; ax0[3] = bv;
        ax1 = ax0;
#pragma unroll
        for (int ks = 0; ks < 16; ++ks) {
            bf16x8 a0 = *(const bf16x8*)&A[r0 * 776 + ks * 32 + q8];
            bf16x8 a1 = *(const bf16x8*)&A[(r0 + 16) * 776 + ks * 32 + q8];
            bf16x8 bf = *(const bf16x8*)(BpX + ks * 32);
            ax0 = __builtin_amdgcn_mfma_f32_16x16x32_bf16(a0, bf, ax0, 0, 0, 0);
            ax1 = __builtin_amdgcn_mfma_f32_16x16x32_bf16(a1, bf, ax1, 0, 0, 0);
        }
    }
    __syncthreads();                             // A free for h staging

    unsigned int* cnt = barrier_cnts + grp * 64; // 256B apart

    for (int step = 0; step < NT; ++step) {
        const unsigned short* hin = hbufs + (size_t)(step % 3) * (2 * NB * NH) + (size_t)dir * NB * NH;
        unsigned short* hout      = hbufs + (size_t)((step + 1) % 3) * (2 * NB * NH) + (size_t)dir * NB * NH;

        // ---- stage h: device-scope (sc1) loads -> LDS ----
        {
            const unsigned short* hr = hin + (size_t)sb * NH;
            unsigned long long hlr[24];
#pragma unroll
            for (int i = 0; i < 12; ++i) {
                unsigned long long* hp = (unsigned long long*)(hr + koff0 + i * 64);
                hlr[2 * i]     = __hip_atomic_load(hp,     __ATOMIC_RELAXED, __HIP_MEMORY_SCOPE_AGENT);
                hlr[2 * i + 1] = __hip_atomic_load(hp + 1, __ATOMIC_RELAXED, __HIP_MEMORY_SCOPE_AGENT);
            }
#pragma unroll
            for (int i = 0; i < 12; ++i) {
                unsigned long long* dp = (unsigned long long*)&A[srow * 776 + koff0 + i * 64];
                dp[0] = hlr[2 * i];
                dp[1] = hlr[2 * i + 1];
            }
        }
        __syncthreads();

        // ---- h-GEMM: acc = (bias + x-part) + h @ Wh ----
        f32x4 acc0, acc1;
        if (mode == 2) {
            acc0[0] = gx[0]; acc0[1] = gx[1]; acc0[2] = gx[2]; acc0[3] = gx[3];
            acc1[0] = gx[4]; acc1[1] = gx[5]; acc1[2] = gx[6]; acc1[3] = gx[7];
        } else {
            acc0 = ax0; acc1 = ax1;
        }
#pragma unroll
        for (int ks = 0; ks < 24; ++ks) {
            bf16x8 a0 = *(const bf16x8*)&A[r0 * 776 + ks * 32 + q8];
            bf16x8 a1 = *(const bf16x8*)&A[(r0 + 16) * 776 + ks * 32 + q8];
            bf16x8 bf = *(const bf16x8*)(WhB + ks * 32);
            acc0 = __builtin_amdgcn_mfma_f32_16x16x32_bf16(a0, bf, acc0, 0, 0, 0);
            acc1 = __builtin_amdgcn_mfma_f32_16x16x32_bf16(a1, bf, acc1, 0, 0, 0);
        }
        __syncthreads();                          // A reads done; gl overlay safe

        // C/D layout: col = lane&15, row = (lane>>4)*4 + reg; gl pitch 17 (pad)
#pragma unroll
        for (int r = 0; r < 4; ++r) {
            gl[(wave * 32 + qq * 4 + r) * 17 + r0] = acc0[r];
            gl[(wave * 32 + 16 + qq * 4 + r) * 17 + r0] = acc1[r];
        }
        __syncthreads();

        // ---- epilogue: cell update; h stores are device-scope (sc1) ----
#pragma unroll
        for (int it = 0; it < 2; ++it) {
            int bl = ebl0 + it * 16;
            int bb = b0 + bl;
            if (step < Lb[it]) {
                float gi = gl[(0 * 32 + bl) * 17 + ehl];
                float gj = gl[(1 * 32 + bl) * 17 + ehl];
                float gf = gl[(2 * 32 + bl) * 17 + ehl];
                float go = gl[(3 * 32 + bl) * 17 + ehl];
                float nc = c_reg[it] * sigmoidf_(gf) + sigmoidf_(gi) * tanhf_(gj);
                float nh = tanhf_(nc) * sigmoidf_(go);
                c_reg[it] = nc;
                h_reg[it] = f2b(nh);
                if (step == Lb[it] - 1)
                    h_final[((size_t)dir * NB + bb) * NH + hidx] = nh;
                int t_out = dir ? (Lb[it] - 1 - step) : step;
                out[((size_t)bb * NT + t_out) * (2 * NH) + dir * NH + hidx] = nh;
            } else {
                out[((size_t)bb * NT + step) * (2 * NH) + dir * NH + hidx] = 0.f;
            }
            __hip_atomic_store(&hout[(size_t)bb * NH + hidx], h_reg[it],
                               __ATOMIC_RELAXED, __HIP_MEMORY_SCOPE_AGENT);
        }

        __syncthreads();    // each wave drains its stores (vmcnt0) before arrive

        // ---- barrier arrive (relaxed: h stores are already L3-visible) ----
        if (tid == 0)
            __hip_atomic_fetch_add(cnt, 1u, __ATOMIC_RELEASE, __HIP_MEMORY_SCOPE_WORKGROUP);

        // ---- pre-poll work for step+1 (hidden under barrier skew) ----
        if (mode == 2) {
            int stepn = step + 1;
#pragma unroll
            for (int i = 0; i < 8; ++i) {
                int tn = dir ? (Ls8[i] - 1 - stepn) : stepn;
                tn = tn < 0 ? 0 : (tn > NT - 1 ? NT - 1 : tn);
                gx[i] = gxp[i][(size_t)tn * 64];
            }
        } else {
            int tn = dir ? (Ls - 2 - step) : (step + 1);
            tn = tn < 0 ? 0 : (tn > NT - 1 ? NT - 1 : tn);
            if (mode == 1) {
                const unsigned short* xr = xrow_b + (size_t)tn * ND;
#pragma unroll
                for (int i = 0; i < 8; ++i) xreg[i] = *(const bf16x8*)(xr + koff0 + i * 64);
            } else {
                const float* xr = xrow_f + (size_t)tn * ND;
#pragma unroll
                for (int i = 0; i < 8; ++i) {
                    float4 v0 = *(const float4*)(xr + koff0 + i * 64);
                    float4 v1 = *(const float4*)(xr + koff0 + i * 64 + 4);
                    bf16x8 o;
                    o[0] = (short)f2b(v0.x); o[1] = (short)f2b(v0.y);
                    o[2] = (short)f2b(v0.z); o[3] = (short)f2b(v0.w);
                    o[4] = (short)f2b(v1.x); o[5] = (short)f2b(v1.y);
                    o[6] = (short)f2b(v1.z); o[7] = (short)f2b(v1.w);
                    xreg[i] = o;
                }
            }
#pragma unroll
            for (int i = 0; i < 8; ++i)
                *(bf16x8*)&A[srow * 776 + koff0 + i * 64] = xreg[i];
            __syncthreads();                      // x(t+1) staged
            ax0[0] = bv; ax0[1] = bv; ax0[2] = bv; ax0[3] = bv;
            ax1 = ax0;
#pragma unroll
            for (int ks = 0; ks < 16; ++ks) {
                bf16x8 a0 = *(const bf16x8*)&A[r0 * 776 + ks * 32 + q8];
                bf16x8 a1 = *(const bf16x8*)&A[(r0 + 16) * 776 + ks * 32 + q8];
                bf16x8 bf = *(const bf16x8*)(BpX + ks * 32);
                ax0 = __builtin_amdgcn_mfma_f32_16x16x32_bf16(a0, bf, ax0, 0, 0, 0);
                ax1 = __builtin_amdgcn_mfma_f32_16x16x32_bf16(a1, bf, ax1, 0, 0, 0);
            }
        }

        // ---- barrier poll (relaxed; h reads are sc1 so no acquire needed) ----
        if (tid == 0) {
            unsigned int tgt = 48u * (unsigned)(step + 1);
            while (__hip_atomic_load(cnt, __ATOMIC_RELAXED, __HIP_MEMORY_SCOPE_AGENT) < tgt)
                __builtin_amdgcn_s_sleep(2);
        }
        __syncthreads();                          // release waves; orders A reuse
    }
}

// ---------------- final hidden state (f32) -> d_out tail ----------------
__global__ __launch_bounds__(256) void write_state(const float* __restrict__ h_final,
                                                   float* __restrict__ out_state) {
    int i = blockIdx.x * 256 + threadIdx.x;      // over 2*NB*NH
    if (i < 2 * NB * NH) {
        int dir = i / (NB * NH);
        int rem = i - dir * (NB * NH);
        int b = rem / NH, h = rem - (rem / NH) * NH;
        out_state[(size_t)b * (2 * NH) + dir * NH + h] = h_final[i];
    }
}

extern "C" void kernel_launch(void* const* d_in, const int* in_sizes, int n_in,
                              void* d_out, int out_size, void* d_ws, size_t ws_size,
                              hipStream_t stream) {
    const float* seq   = (const float*)d_in[0];
    const int* seq_len = (const int*)d_in[1];
    const float* W_fw  = (const float*)d_in[2];
    const float* b_fw  = (const float*)d_in[3];
    const float* W_bw  = (const float*)d_in[4];
    const float* b_bw  = (const float*)d_in[5];
    float* out = (float*)d_out;

    char* ws = (char*)d_ws;
    size_t off = 0;
    unsigned short* WT = (unsigned short*)(ws + off);  off += (size_t)2 * NG * KTOT * 2; // 15,728,640
    unsigned short* hbufs = (unsigned short*)(ws + off);
    size_t hbuf_bytes = (size_t)3 * 2 * NB * NH * 2;   off += hbuf_bytes;                // 589,824
    float* h_final = (float*)(ws + off);
    size_t hf_bytes = (size_t)2 * NB * NH * 4;         off += hf_bytes;                  // 393,216
    unsigned int* barrier_cnts = (unsigned int*)(ws + off);
    size_t bar_bytes = 1024;                           off += bar_bytes;

    // Gx and xbf share the workspace tail (only one is used).
    float* Gx = (float*)(ws + off);
    size_t gx_bytes = (size_t)2 * NHG * NROW * 64 * 4;   // 805,306,368
    unsigned short* xbf = (unsigned short*)(ws + off);
    size_t xbf_bytes = (size_t)NB * NT * ND * 2;         // 33,554,432

    int mode = (ws_size >= off + gx_bytes) ? 2
             : ((ws_size >= off + xbf_bytes) ? 1 : 0);

    // zero h buffers / h_final / barrier counters (contiguous)
    hipMemsetAsync(hbufs, 0, hbuf_bytes + hf_bytes + bar_bytes, stream);

    transpose_w<<<(KTOT / 64) * (NG / 64), 256, 0, stream>>>(W_fw, WT);
    transpose_w<<<(KTOT / 64) * (NG / 64), 256, 0, stream>>>(W_bw, WT + (size_t)NG * KTOT);

    if (mode == 2) {
        gemm_xw<<<1024, 256, 0, stream>>>(seq, WT, b_fw, b_bw, Gx);
    } else if (mode == 1) {
        int n8 = NB * NT * ND / 8;
        convert_x<<<(n8 + 255) / 256, 256, 0, stream>>>(seq, xbf, n8);
    }

    size_t smem_bytes = (size_t)64 * 776 * 2 + (size_t)32 * 776 * 2;   // 148,992
    lstm_persistent<<<192, 256, smem_bytes, stream>>>(
        seq, xbf, mode, seq_len, WT, b_fw, b_bw, Gx,
        hbufs, h_final, out, barrier_cnts);

    write_state<<<(2 * NB * NH + 255) / 256, 256, 0, stream>>>(
        h_final, out + (size_t)NB * NT * 2 * NH);
}